// Round 1
// baseline (698.348 us; speedup 1.0000x reference)
//
#include <hip/hip_runtime.h>

// ---------------------------------------------------------------------------
// lm_ot: LM softmax distributions + Sinkhorn OT, fused pipeline for MI355X.
// Sizes fixed by setup_inputs(): B=512, H=1024, V=28996, NV=3000, SLOTS=33.
// R6: sinkhorn matvecs moved onto the matrix pipe. Previous VALU kpass
//     (516 instr/thread/iter, MfmaUtil 0%) replaced by mfma_f32_16x16x32_bf16:
//     W-pass  w = Kb[3008x32] @ Ub  (Ub cols: u_hi0,u_hi1,u_lo0,u_lo1),
//     Z-pass  z = KbT[32x3008] @ Tb (Tb cols: t_hi0,t_hi1,t_lo0,t_lo1).
//     u,t carried as double-bf16 (hi+lo) => trajectory matches f32 path ~1e-5.
//     t kept in f32 in LDS for errpass/epilogue (same numerics as old vsh).
// ---------------------------------------------------------------------------
#define NV 3000
#define HH 1024
#define BB 512

typedef __attribute__((ext_vector_type(8))) short short8;
typedef __attribute__((ext_vector_type(4))) float floatx4;

__device__ __forceinline__ float wave_sum(float x) {
#pragma unroll
  for (int off = 32; off; off >>= 1) x += __shfl_xor(x, off, 64);
  return x;
}
__device__ __forceinline__ unsigned bf16r(float x) {  // fp32 -> bf16 bits, RNE
  unsigned u = __float_as_uint(x);
  u += 0x7fffu + ((u >> 16) & 1u);
  return u >> 16;
}
__device__ __forceinline__ void gload16(const void* g, void* l) {
  // async global->LDS DMA; HW dst = wave-uniform base + lane*16B.
  __builtin_amdgcn_global_load_lds(
      (const __attribute__((address_space(1))) unsigned*)g,
      (__attribute__((address_space(3))) unsigned*)l, 16, 0, 0);
}

// --- norms of gathered W rows + topics, AND bf16 gather Wb[3072][1024] ------
__global__ __launch_bounds__(256) void norms_wb_kernel(
    const float* __restrict__ W_lm, const float* __restrict__ topics,
    const int* __restrict__ verbs, float* __restrict__ vninv,
    float* __restrict__ tninv, unsigned short* __restrict__ Wb) {
  int r = blockIdx.x, t = threadIdx.x;
  bool isW = r < 3072;
  int j = isW ? (r < NV ? r : NV - 1) : 0;
  const float* src = isW ? (W_lm + (size_t)verbs[j] * HH)
                         : (topics + (size_t)(r - 3072) * HH);
  float4 v = *(const float4*)(src + t * 4);
  if (isW) {
    *(uint2*)(Wb + (size_t)r * HH + t * 4) =
        make_uint2(bf16r(v.x) | (bf16r(v.y) << 16),
                   bf16r(v.z) | (bf16r(v.w) << 16));
  }
  float ss = v.x * v.x + v.y * v.y + v.z * v.z + v.w * v.w;
  ss = wave_sum(ss);
  __shared__ float sq[4];
  if ((t & 63) == 0) sq[t >> 6] = ss;
  __syncthreads();
  if (t == 0) {
    float inv = 1.0f / (sqrtf(sq[0] + sq[1] + sq[2] + sq[3]) + 1e-8f);
    if (isW) { if (r < NV) vninv[r] = inv; }
    else tninv[r - 3072] = inv;
  }
}

// --- Xb[1024][1024] bf16: rows 0..511 = inputs[:, :1024], 512.. = [:,1024:] -
__global__ __launch_bounds__(256) void xb_kernel(
    const float* __restrict__ inputs, unsigned short* __restrict__ Xb) {
  int idx = blockIdx.x * 256 + threadIdx.x;  // < 131072
  int r = idx >> 7, c8 = (idx & 127) << 3;
  const float* src = (r < 512) ? (inputs + (size_t)r * 2048 + c8)
                               : (inputs + (size_t)(r - 512) * 2048 + 1024 + c8);
  float4 x0 = ((const float4*)src)[0];
  float4 x1 = ((const float4*)src)[1];
  uint4 o;
  o.x = bf16r(x0.x) | (bf16r(x0.y) << 16);
  o.y = bf16r(x0.z) | (bf16r(x0.w) << 16);
  o.z = bf16r(x1.x) | (bf16r(x1.y) << 16);
  o.w = bf16r(x1.z) | (bf16r(x1.w) << 16);
  *(uint4*)(Xb + (size_t)r * HH + c8) = o;
}

// --- topT[k][s] = topics[s][k] * tninv[s]  (transposed+scaled, 1024x32) -----
__global__ __launch_bounds__(256) void topt_kernel(
    const float* __restrict__ topics, const float* __restrict__ tninv,
    float* __restrict__ topT) {
  int idx = blockIdx.x * 256 + threadIdx.x;  // = k*32 + s, < 32768
  int k = idx >> 5, s = idx & 31;
  topT[idx] = topics[(size_t)s * HH + k] * tninv[s];
}

// --- aT[row][0..31] = softmax((outputs @ W_lin^T + b_lin)[row, 1:33]) -------
__global__ __launch_bounds__(64) void a_kernel(
    const float* __restrict__ outputs, const float* __restrict__ W_lin,
    const float* __restrict__ b_lin, float* __restrict__ aT) {
  int r = blockIdx.x, t = threadIdx.x;
  __shared__ float orow[512];
  __shared__ float lg[33];
  __shared__ float ms[2];
  *(float4*)(orow + t * 8)     = *(const float4*)(outputs + (size_t)r * 512 + t * 8);
  *(float4*)(orow + t * 8 + 4) = *(const float4*)(outputs + (size_t)r * 512 + t * 8 + 4);
  __syncthreads();
  if (t < 33) {
    float acc = b_lin[t];
    for (int k = 0; k < 512; ++k) acc = fmaf(orow[k], W_lin[(size_t)t * 512 + k], acc);
    lg[t] = acc;
  }
  __syncthreads();
  if (t == 0) {
    float m = lg[1];
    for (int i = 2; i < 33; ++i) m = fmaxf(m, lg[i]);
    float ssum = 0.0f;
    for (int i = 1; i < 33; ++i) ssum += __expf(lg[i] - m);
    ms[0] = m; ms[1] = ssum;
  }
  __syncthreads();
  if (t >= 1 && t < 33) aT[(size_t)r * 32 + t - 1] = __expf(lg[t] - ms[0]) / ms[1];
}

// --- MFMA logits GEMM: L[1024][3000] = 0.5 * Xb @ Wb^T  (bf16 in, f32 out) --
__global__ __launch_bounds__(256) void gemm_mfma(
    const unsigned short* __restrict__ Xb, const unsigned short* __restrict__ Wb,
    float* __restrict__ L) {
  __shared__ unsigned short As[128 * 32], Bs[128 * 32];
  int t = threadIdx.x;
  int wave = t >> 6, ln = t & 63;
  int bn = blockIdx.x, bm = blockIdx.y;
  int wm = (wave >> 1) * 64, wn = (wave & 1) * 64;
  const unsigned short* ga = Xb + (size_t)(bm * 128 + (t >> 2)) * HH + (t & 3) * 8;
  const unsigned short* gb = Wb + (size_t)(bn * 128 + (t >> 2)) * HH + (t & 3) * 8;
  int lq = ln >> 4, lm = ln & 15;
  floatx4 acc[4][4];
#pragma unroll
  for (int i = 0; i < 4; ++i)
#pragma unroll
    for (int j = 0; j < 4; ++j) acc[i][j] = (floatx4)0.0f;

  for (int k0 = 0; k0 < HH; k0 += 32) {
    __syncthreads();
    gload16(ga + k0, As + t * 8);
    gload16(ga + (size_t)64 * HH + k0, As + 2048 + t * 8);
    gload16(gb + k0, Bs + t * 8);
    gload16(gb + (size_t)64 * HH + k0, Bs + 2048 + t * 8);
    __syncthreads();
    short8 af[4], bfr[4];
#pragma unroll
    for (int i = 0; i < 4; ++i)
      af[i] = *(const short8*)(As + (wm + i * 16 + lm) * 32 + lq * 8);
#pragma unroll
    for (int j = 0; j < 4; ++j)
      bfr[j] = *(const short8*)(Bs + (wn + j * 16 + lm) * 32 + lq * 8);
#pragma unroll
    for (int i = 0; i < 4; ++i)
#pragma unroll
      for (int j = 0; j < 4; ++j)
        acc[i][j] = __builtin_amdgcn_mfma_f32_16x16x32_bf16(af[i], bfr[j], acc[i][j], 0, 0, 0);
  }
  int row0 = bm * 128 + wm + lq * 4;
  int col0 = bn * 128 + wn + lm;
#pragma unroll
  for (int j = 0; j < 4; ++j) {
    int col = col0 + j * 16;
    if (col < NV) {
#pragma unroll
      for (int i = 0; i < 4; ++i) {
#pragma unroll
        for (int r = 0; r < 4; ++r)
          L[(size_t)(row0 + i * 16 + r) * NV + col] = acc[i][j][r] * 0.5f;
      }
    }
  }
}

// --- per-row: bT = renorm(0.5*(softmax(L1)+softmax(L2))), in-place over L1 ---
__global__ __launch_bounds__(256) void softmax_kernel(
    float* __restrict__ L1, const float* __restrict__ L2) {
  int r = blockIdx.x, t = threadIdx.x, w = t >> 6, ln = t & 63;
  float* row1 = L1 + (size_t)r * NV;
  const float* row2 = L2 + (size_t)r * NV;
  __shared__ float rd[2][4];
  float s1 = 0.0f, s2 = 0.0f;
  for (int v = t; v < NV; v += 256) { s1 += __expf(row1[v]); s2 += __expf(row2[v]); }
  s1 = wave_sum(s1); s2 = wave_sum(s2);
  if (ln == 0) { rd[0][w] = s1; rd[1][w] = s2; }
  __syncthreads();
  s1 = rd[0][0] + rd[0][1] + rd[0][2] + rd[0][3];
  s2 = rd[1][0] + rd[1][1] + rd[1][2] + rd[1][3];
  float i1 = 0.5f / s1, i2 = 0.5f / s2;
  float rs = 0.0f;
  for (int v = t; v < NV; v += 256) {
    float o = __expf(row1[v]) * i1 + __expf(row2[v]) * i2;
    row1[v] = o; rs += o;
  }
  rs = wave_sum(rs);
  __syncthreads();
  if (ln == 0) rd[0][w] = rs;
  __syncthreads();
  float rinv = 1.0f / (rd[0][0] + rd[0][1] + rd[0][2] + rd[0][3]);
  for (int v = t; v < NV; v += 256) row1[v] *= rinv;
}

// --- Kb[v][s]=bf16(K) row-major [3008][32], KbT[s][v] bf16 [32][3008],
//     KMt[v][s]=K*M fp32. Rows/cols >= NV zero-padded. ----------------------
__global__ __launch_bounds__(256) void mk_kernel(
    const float* __restrict__ W_lm, const int* __restrict__ verbs,
    const float* __restrict__ topT, const float* __restrict__ vninv,
    unsigned* __restrict__ Kb, unsigned short* __restrict__ KbT,
    float* __restrict__ KMt) {
  __shared__ float red[4][64][33];
  int t = threadIdx.x, ln = t & 63, w = t >> 6;
  int v = blockIdx.x * 64 + ln;
  int vc = v < NV ? v : NV - 1;
  int kb = __builtin_amdgcn_readfirstlane(w) << 8;
  const float* wrow = W_lm + (size_t)verbs[vc] * HH + kb;
  const float* tb = topT + (size_t)kb * 32;
  float acc[32];
#pragma unroll
  for (int s = 0; s < 32; ++s) acc[s] = 0.0f;
  for (int kk = 0; kk < 256; kk += 4) {
    float4 w4 = *(const float4*)(wrow + kk);
    const float* tr = tb + kk * 32;
    const float* pw = (const float*)&w4;
#pragma unroll
    for (int d = 0; d < 4; ++d)
#pragma unroll
      for (int s = 0; s < 32; ++s) acc[s] = fmaf(pw[d], tr[d * 32 + s], acc[s]);
  }
#pragma unroll
  for (int s = 0; s < 32; ++s) red[w][ln][s] = acc[s];
  __syncthreads();
  for (int idx = t; idx < 1024; idx += 256) {
    int l = idx >> 4, pr = idx & 15;
    int vo = blockIdx.x * 64 + l;
    int s0 = pr * 2, s1 = s0 + 1;
    if (vo < NV) {
      float vi = vninv[vo];
      float d0 = red[0][l][s0] + red[1][l][s0] + red[2][l][s0] + red[3][l][s0];
      float d1 = red[0][l][s1] + red[1][l][s1] + red[2][l][s1] + red[3][l][s1];
      float M0 = 1.0f - d0 * vi, M1 = 1.0f - d1 * vi;
      float K0 = __expf(-20.0f * M0), K1 = __expf(-20.0f * M1);
      *(float2*)(KMt + (size_t)vo * 32 + s0) = make_float2(K0 * M0, K1 * M1);
      unsigned b0 = bf16r(K0), b1 = bf16r(K1);
      Kb[(size_t)vo * 16 + pr] = b0 | (b1 << 16);
      KbT[(size_t)s0 * 3008 + vo] = (unsigned short)b0;
      KbT[(size_t)s1 * 3008 + vo] = (unsigned short)b1;
    } else {  // pad rows 3000..3007
      Kb[(size_t)vo * 16 + pr] = 0u;
      KbT[(size_t)s0 * 3008 + vo] = 0;
      KbT[(size_t)s1 * 3008 + vo] = 0;
    }
  }
}

// --- manual grid barrier: monotone counter, agent-scope atomics -------------
__device__ __forceinline__ void gridbar(unsigned* bar, unsigned target) {
  __syncthreads();
  if (threadIdx.x == 0) {
    __hip_atomic_fetch_add(bar, 1u, __ATOMIC_RELEASE, __HIP_MEMORY_SCOPE_AGENT);
    while (__hip_atomic_load(bar, __ATOMIC_ACQUIRE, __HIP_MEMORY_SCOPE_AGENT) < target) {
      __builtin_amdgcn_s_sleep(1);
    }
  }
  __syncthreads();
}

// 16-element reduce-scatter butterfly over strides 2..32 (epilogue only).
__device__ __forceinline__ float waveRS16(float* z, int ln) {
  int cnt = 16;
#pragma unroll
  for (int d = 2; d <= 16; d <<= 1) {
    int half = cnt >> 1;
    bool hi = (ln & d) != 0;
#pragma unroll
    for (int k = 0; k < 8; ++k) {
      if (k < half) {
        float a = z[k], b = z[half + k];
        z[k] = hi ? b : a;
        z[half + k] = hi ? a : b;
      }
    }
#pragma unroll
    for (int k = 0; k < 8; ++k)
      if (k < half) z[k] += __shfl_xor(z[half + k], d, 64);
    cnt = half;
  }
  return z[0] + __shfl_xor(z[0], 32, 64);
}

// --- Sinkhorn: 256 blocks x 1024 threads; 2 columns per block, MFMA core ----
// Per iteration:
//   W:  per 16-row chunk, A-frag = Kb rows (coalesced 16B/lane),
//       B cols {0,1,2,3} = {u_hi0,u_hi1,u_lo0,u_lo1}; lanes lm<4 store the
//       4-col partials (w = hi-part + lo-part, combined in t-phase).
//   t:  all threads: w -> t = b*rcp(w); store f32 t (errpass/epilogue) and
//       hi/lo bf16 (Z-pass B operand). Pad rows get t = 0.
//   Z:  A-frags from KbT (slots x v), B cols = t hi/lo; col0+col2 combined
//       via shfl_xor(2); per-wave partial z reduced through LDS by t<64.
__global__ __launch_bounds__(1024) void sinkhorn_kernel(
    const unsigned short* __restrict__ Kb, const unsigned short* __restrict__ KbT,
    const float* __restrict__ KMt, const float* __restrict__ bT,
    const float* __restrict__ aT, unsigned* __restrict__ slots,
    float* __restrict__ outp) {
  const int t = threadIdx.x;
  const int wv = t >> 6, ln = t & 63;
  const int lm = ln & 15, lq = ln >> 4;
  const int p = t & 1, pid = t >> 1;
  const int col0 = blockIdx.x << 1;
  const float* b0r = bT + (size_t)col0 * NV;
  const float* b1r = b0r + NV;
  float* accres = (float*)(slots + 64);
  unsigned* bar = slots + 65;

  __shared__ __align__(16) float wshp0[3008], wshp1[3008];
  __shared__ __align__(16) unsigned short wtbuf[4][3008];  // h0,h1,l0,l1 after t-phase
  __shared__ __align__(16) float zred[16][2][32];
  __shared__ float ushf[64];
  __shared__ __align__(16) unsigned short ub[4][32];       // uh0,uh1,ul0,ul1
  __shared__ float sredA[16], sredB[16];
  __shared__ unsigned ebits;

  // W-phase scratch: cols 2,3 (u_lo partials) alias the (dead) wtbuf region.
  float* wlo0 = (float*)&wtbuf[0][0];
  float* wlo1 = (float*)&wtbuf[2][0];
  float* wbase = (lm == 0) ? wshp0 : (lm == 1) ? wshp1 : (lm == 2) ? wlo0 : wlo1;
  const unsigned short* zbsel = &wtbuf[lm & 3][0];
  const unsigned short* ubsel = &ub[lm & 3][0];

  const int sl = ((ln & 1) << 4) | ((ln & 2) << 2) | (ln & 4) |
                 ((ln & 8) >> 2) | ((ln & 16) >> 4);

  float areg = (t < 64) ? aT[(size_t)col0 * 32 + t] : 0.0f;
  if (t < 64) {
    int c = t >> 5, s = t & 31;
    ushf[t] = 1.0f / 32.0f;
    ub[c][s] = (unsigned short)0x3D00u;  // bf16(1/32), exact
    ub[2 + c][s] = 0;
  }
  __syncthreads();

  float err = 1.0f;
  int cpt = 0, chk = 0;
  unsigned barcnt = 0;

  auto full_iter = [&]() {
    // ---- W-pass ----
    {
      short8 bfu = *(const short8*)(ubsel + (lq << 3));
#pragma unroll
      for (int i = 0; i < 12; ++i) {
        int c = wv + (i << 4);
        if (c < 188) {
          int v0 = c << 4;
          short8 af = *(const short8*)(Kb + (size_t)(v0 + lm) * 32 + (lq << 3));
          floatx4 acc = (floatx4)0.0f;
          acc = __builtin_amdgcn_mfma_f32_16x16x32_bf16(af, bfu, acc, 0, 0, 0);
          if (lm < 4) *(floatx4*)(wbase + v0 + (lq << 2)) = acc;
        }
      }
    }
    __syncthreads();
    // ---- t-phase (A: read w-partials, compute; B: write t after barrier) ----
    float t0r[3], t1r[3];
#pragma unroll
    for (int i = 0; i < 3; ++i) {
      int v = t + (i << 10);
      t0r[i] = 0.0f; t1r[i] = 0.0f;
      if (v < NV) {
        float w0 = wshp0[v] + wlo0[v];
        float w1 = wshp1[v] + wlo1[v];
        t0r[i] = b0r[v] * __builtin_amdgcn_rcpf(w0);
        t1r[i] = b1r[v] * __builtin_amdgcn_rcpf(w1);
      }
    }
    __syncthreads();
#pragma unroll
    for (int i = 0; i < 3; ++i) {
      int v = t + (i << 10);
      if (v < 3008) {
        float T0 = t0r[i], T1 = t1r[i];
        unsigned h0 = bf16r(T0), h1 = bf16r(T1);
        wtbuf[0][v] = (unsigned short)h0;
        wtbuf[1][v] = (unsigned short)h1;
        wtbuf[2][v] = (unsigned short)bf16r(T0 - __uint_as_float(h0 << 16));
        wtbuf[3][v] = (unsigned short)bf16r(T1 - __uint_as_float(h1 << 16));
        wshp0[v] = T0; wshp1[v] = T1;  // f32 t for errpass/epilogue
      }
    }
    __syncthreads();
    // ---- Z-pass ----
    floatx4 accL = (floatx4)0.0f, accH = (floatx4)0.0f;
#pragma unroll
    for (int i = 0; i < 6; ++i) {
      int c = wv + (i << 4);
      if (c < 94) {
        int v0 = c << 5;
        short8 aL = *(const short8*)(KbT + (size_t)lm * 3008 + v0 + (lq << 3));
        short8 aH = *(const short8*)(KbT + (size_t)(lm + 16) * 3008 + v0 + (lq << 3));
        short8 bt = *(const short8*)(zbsel + v0 + (lq << 3));
        accL = __builtin_amdgcn_mfma_f32_16x16x32_bf16(aL, bt, accL, 0, 0, 0);
        accH = __builtin_amdgcn_mfma_f32_16x16x32_bf16(aH, bt, accH, 0, 0, 0);
      }
    }
    floatx4 zL, zH;
#pragma unroll
    for (int r = 0; r < 4; ++r) {
      zL[r] = accL[r] + __shfl_xor(accL[r], 2, 64);
      zH[r] = accH[r] + __shfl_xor(accH[r], 2, 64);
    }
    if (lm < 2) {
      *(floatx4*)&zred[wv][lm][lq << 2] = zL;
      *(floatx4*)&zred[wv][lm][16 + (lq << 2)] = zH;
    }
    __syncthreads();
    if (t < 64) {
      int c = t >> 5, s = t & 31;
      float zz = 0.0f;
#pragma unroll
      for (int k = 0; k < 16; ++k) zz += zred[k][c][s];
      float uu = areg * __builtin_amdgcn_rcpf(zz);
      ushf[t] = uu;
      unsigned h = bf16r(uu);
      ub[c][s] = (unsigned short)h;
      ub[2 + c][s] = (unsigned short)bf16r(uu - __uint_as_float(h << 16));
    }
    __syncthreads();
  };

  while (cpt < 1000 && err > 0.005f) {
    full_iter();
    ++cpt;
    if (cpt % 20 == 1 || cpt == 1000) {
      full_iter();  // check: v = b/(K^T u) (stored), u = a/(K v)
      // ---- error pass: w' = K^T u_new; err = max_col sum |t*w' - b| ----
      float ep0 = 0.0f, ep1 = 0.0f;
      {
        short8 bfu = *(const short8*)(ubsel + (lq << 3));
#pragma unroll
        for (int i = 0; i < 12; ++i) {
          int c = wv + (i << 4);
          if (c < 188) {
            int v0 = c << 4;
            short8 af = *(const short8*)(Kb + (size_t)(v0 + lm) * 32 + (lq << 3));
            floatx4 acc = (floatx4)0.0f;
            acc = __builtin_amdgcn_mfma_f32_16x16x32_bf16(af, bfu, acc, 0, 0, 0);
#pragma unroll
            for (int r = 0; r < 4; ++r) {
              float wq = acc[r] + __shfl_xor(acc[r], 2, 64);
              int v = v0 + (lq << 2) + r;
              if (lm < 2 && v < NV) {
                float tt = (lm == 0) ? wshp0[v] : wshp1[v];
                float bb = (lm == 0) ? b0r[v] : b1r[v];
                float e = fabsf(tt * wq - bb);
                if (lm == 0) ep0 += e; else ep1 += e;
              }
            }
          }
        }
      }
      ep0 = wave_sum(ep0); ep1 = wave_sum(ep1);
      if (ln == 0) { sredA[wv] = ep0; sredB[wv] = ep1; }
      __syncthreads();
      if (t == 0) {
        float e0 = 0.0f, e1 = 0.0f;
#pragma unroll
        for (int k = 0; k < 16; ++k) { e0 += sredA[k]; e1 += sredB[k]; }
        atomicMax(slots + chk, __float_as_uint(fmaxf(e0, e1)));
      }
      ++barcnt;
      gridbar(bar, barcnt * 256u);
      if (t == 0) ebits = __hip_atomic_load(slots + chk, __ATOMIC_RELAXED, __HIP_MEMORY_SCOPE_AGENT);
      __syncthreads();
      err = __uint_as_float(ebits);
      ++chk;
    }
  }

  // ---- epilogue: out_col = sum_s u[s] * sum_v KM[v][s]*t[v] ----
  float y0[16], y1[16];
#pragma unroll
  for (int s = 0; s < 16; ++s) { y0[s] = 0.0f; y1[s] = 0.0f; }
#pragma unroll 3
  for (int i = 0; i < 6; ++i) {
    int v = pid + (i << 9);
    if (i < 5 || v < NV) {
      const floatx4* kp = (const floatx4*)(KMt + (size_t)v * 32 + (p << 4));
      float kc[16];
#pragma unroll
      for (int q = 0; q < 4; ++q) *(floatx4*)(kc + q * 4) = kp[q];
      float x0 = wshp0[v], x1 = wshp1[v];
#pragma unroll
      for (int s = 0; s < 16; ++s) { y0[s] = fmaf(kc[s], x0, y0[s]); y1[s] = fmaf(kc[s], x1, y1[s]); }
    }
  }
  float r0 = waveRS16(y0, ln), r1 = waveRS16(y1, ln);
  __syncthreads();
  if (ln < 32) { zred[wv][0][sl] = r0; zred[wv][1][sl] = r1; }
  __syncthreads();
  if (t < 64) {
    int c = t >> 5, s = t & 31;
    float ys = 0.0f;
#pragma unroll
    for (int k = 0; k < 16; ++k) ys += zred[k][c][s];
    float pp = ys * ushf[t];
#pragma unroll
    for (int off = 1; off <= 16; off <<= 1) pp += __shfl_xor(pp, off, 64);
    float other = __shfl_xor(pp, 32, 64);
    if (t == 0) atomicAdd(accres, pp + other);
  }
  ++barcnt;
  gridbar(bar, barcnt * 256u);
  if (blockIdx.x == 0 && t == 0) {
    unsigned ab = __hip_atomic_load((unsigned*)accres, __ATOMIC_RELAXED, __HIP_MEMORY_SCOPE_AGENT);
    outp[0] = __uint_as_float(ab) / 512.0f;
  }
}

// ---------------------------------------------------------------------------
extern "C" void kernel_launch(void* const* d_in, const int* in_sizes, int n_in,
                              void* d_out, int out_size, void* d_ws, size_t ws_size,
                              hipStream_t stream) {
  (void)in_sizes; (void)n_in; (void)out_size; (void)ws_size;
  const float* inputs  = (const float*)d_in[0];
  const float* outputs = (const float*)d_in[1];
  const float* W_lm    = (const float*)d_in[2];
  const float* W_lin   = (const float*)d_in[3];
  const float* b_lin   = (const float*)d_in[4];
  const float* topics  = (const float*)d_in[5];
  const int*   verbs   = (const int*)d_in[6];
  float* out = (float*)d_out;

  char* ws = (char*)d_ws;
  float*    L     = (float*)(ws);                 // 12,288,000 B (1024x3000)
  float*    L1    = L;                            //   rows 0..511 (becomes bT)
  float*    L2    = (float*)(ws + 6144000);       //   rows 512..1023
  float*    aT    = (float*)(ws + 12288000);      //     65,536 B
  unsigned* Kb    = (unsigned*)(ws + 12353536);   //    192,512 B (bf16 x2, 3008 rows)
  float*    KMt   = (float*)(ws + 12546048);      //    384,000 B
  float*    topT  = (float*)(ws + 12930048);      //    131,072 B
  float*    vninv = (float*)(ws + 13061120);      //     12,032 B
  float*    tninv = (float*)(ws + 13073152);      //        128 B
  unsigned* slots = (unsigned*)(ws + 13073280);   //        512 B
  unsigned short* Xb  = (unsigned short*)(ws + 13073792);  // 2,097,152 B
  unsigned short* Wb  = (unsigned short*)(ws + 15170944);  // 6,291,456 B
  unsigned short* KbT = (unsigned short*)(ws + 21462400);  //   192,512 B

  hipMemsetAsync((void*)slots, 0, 512, stream);

  norms_wb_kernel<<<3104, 256, 0, stream>>>(W_lm, topics, verbs, vninv, tninv, Wb);
  xb_kernel<<<512, 256, 0, stream>>>(inputs, Xb);
  topt_kernel<<<128, 256, 0, stream>>>(topics, tninv, topT);
  a_kernel<<<BB, 64, 0, stream>>>(outputs, W_lin, b_lin, aT);
  gemm_mfma<<<dim3(24, 8), 256, 0, stream>>>(Xb, Wb, L);
  softmax_kernel<<<BB, 256, 0, stream>>>(L1, L2);
  mk_kernel<<<47, 256, 0, stream>>>(W_lm, verbs, topT, vninv, Kb, KbT, KMt);
  sinkhorn_kernel<<<256, 1024, 0, stream>>>((const unsigned short*)Kb, KbT, KMt,
                                            /*bT=*/L1, aT, slots, out);
}